// Round 1
// baseline (2699.919 us; speedup 1.0000x reference)
//
#include <hip/hip_runtime.h>
#include <math.h>

// TransFusionHead anchor matching — full pipeline, fp32, correctness-first.
// Pipeline: wT transposes -> conv1(512->128,+bias) -> conv2(128->128,BN+ReLU)
//   -> conv3(128->60)+threshold-sigmoid+norm+anchor-sim+sigmoid -> heatmap (d_out)
//   -> NMS -> radix-select top-200 (exact jax.lax.top_k tie order) -> gathers.
// Workspace use: ~72.2 MB.

#define HW 180
#define NPIX 32400          // 180*180
#define NCLS 10
#define NPROP 200
#define HID 128
#define TDIM 60
#define NBIG (NCLS*NPIX)    // 324000 per batch

// linspace(log(ANCHORS).min()-0.1, log(ANCHORS).max()-0.1, 20), tiled x3
#define TH_LO  (-0.9915981193)
#define TH_STEP (0.1789675812)

__constant__ float c_anchors[10][3] = {
  {4.63f,1.97f,1.74f},{6.93f,2.51f,2.84f},{6.37f,2.85f,3.19f},{10.5f,2.94f,3.47f},
  {12.29f,2.9f,3.87f},{0.5f,2.53f,0.98f},{2.11f,0.77f,1.47f},{1.7f,0.6f,1.28f},
  {0.73f,0.67f,1.77f},{0.41f,0.41f,1.07f}};

// dst[c][t][co] = src[co][c][t]  (zero-pad co >= cout)
__global__ void transpose_w_kernel(const float* __restrict__ src, float* __restrict__ dst,
                                   int cin, int cout, int cobt) {
  int i = blockIdx.x * 256 + threadIdx.x;
  int n = cin * 9 * cobt;
  if (i >= n) return;
  int co = i % cobt;
  int t  = (i / cobt) % 9;
  int c  = i / (cobt * 9);
  dst[i] = (co < cout) ? src[((size_t)co * cin + c) * 9 + t] : 0.f;
}

// 3x3 SAME conv. Tile: 4 rows x 64 cols x 64 couts. 256 thr: co_g=t&15 (4 couts),
// pg=t>>4 (4x4 pixel sub-tile). EPI 0: +bias(p0). EPI 1: relu(x*p0+p1).
template<int CIN, int EPI>
__global__ __launch_bounds__(256, 2)
void conv3x3_kernel(const float* __restrict__ in, const float* __restrict__ wT,
                    const float* __restrict__ p0, const float* __restrict__ p1,
                    float* __restrict__ out, int cobTot) {
  __shared__ float lds_in[8][6][68];
  const int x0 = blockIdx.x * 64;
  const int y0 = blockIdx.y * 4;
  const int halves = cobTot >> 6;
  const int b   = blockIdx.z / halves;
  const int co0 = (blockIdx.z % halves) * 64;
  const int tid  = threadIdx.x;
  const int co_g = tid & 15;
  const int pg   = tid >> 4;
  const int pxb  = pg * 4;

  float acc[4][4][4];
#pragma unroll
  for (int a = 0; a < 4; ++a)
#pragma unroll
    for (int yy = 0; yy < 4; ++yy)
#pragma unroll
      for (int xx = 0; xx < 4; ++xx) acc[a][yy][xx] = 0.f;

  for (int c0 = 0; c0 < CIN; c0 += 8) {
    __syncthreads();
    for (int i = tid; i < 8 * 6 * 68; i += 256) {
      int ch = i / (6 * 68); int rem = i - ch * (6 * 68);
      int r = rem / 68; int xx = rem - r * 68;
      int y = y0 + r - 1; int x = x0 + xx - 1;
      float v = 0.f;
      if (xx < 66 && (unsigned)y < (unsigned)HW && (unsigned)x < (unsigned)HW)
        v = in[(((size_t)b * CIN + (c0 + ch)) * HW + y) * HW + x];
      lds_in[ch][r][xx] = v;
    }
    __syncthreads();
    for (int ch = 0; ch < 8; ++ch) {
      float rin[6][6];
#pragma unroll
      for (int rr = 0; rr < 6; ++rr) {
        const float2* rp = (const float2*)&lds_in[ch][rr][pxb];
        float2 v0 = rp[0], v1 = rp[1], v2 = rp[2];
        rin[rr][0] = v0.x; rin[rr][1] = v0.y; rin[rr][2] = v1.x;
        rin[rr][3] = v1.y; rin[rr][4] = v2.x; rin[rr][5] = v2.y;
      }
      const float* wrow = wT + (size_t)(c0 + ch) * 9 * cobTot + co0 + co_g * 4;
#pragma unroll
      for (int t = 0; t < 9; ++t) {
        const float4 w4 = *reinterpret_cast<const float4*>(wrow + (size_t)t * cobTot);
        const int ky = t / 3, kx = t % 3;
#pragma unroll
        for (int yy = 0; yy < 4; ++yy)
#pragma unroll
          for (int xx = 0; xx < 4; ++xx) {
            const float iv = rin[yy + ky][xx + kx];
            acc[0][yy][xx] = fmaf(iv, w4.x, acc[0][yy][xx]);
            acc[1][yy][xx] = fmaf(iv, w4.y, acc[1][yy][xx]);
            acc[2][yy][xx] = fmaf(iv, w4.z, acc[2][yy][xx]);
            acc[3][yy][xx] = fmaf(iv, w4.w, acc[3][yy][xx]);
          }
      }
    }
  }
  const int xbase = x0 + pxb;
  if (xbase >= HW) return;
#pragma unroll
  for (int co = 0; co < 4; ++co) {
    const int c = co0 + co_g * 4 + co;
    const float g0 = p0[c];
    const float g1 = (EPI == 1) ? p1[c] : 0.f;
#pragma unroll
    for (int yy = 0; yy < 4; ++yy) {
      float4 vv;
      float* pv = &vv.x;
#pragma unroll
      for (int xx = 0; xx < 4; ++xx) {
        float v = acc[co][yy][xx];
        if (EPI == 0) v = v + g0;
        else { v = fmaf(v, g0, g1); v = fmaxf(v, 0.f); }
        pv[xx] = v;
      }
      *reinterpret_cast<float4*>(out + (((size_t)b * cobTot + c) * HW + (y0 + yy)) * HW + xbase) = vv;
    }
  }
}

// conv3 (128->60, padded to 64 couts) fused with threshold-sigmoid, per-pixel
// L2 norm, anchor cosine sim, logit sigmoid. One block holds all 60 channels;
// per-pixel reduce across the 16 consecutive co_g lanes via shfl_xor(width 16).
__global__ __launch_bounds__(256, 2)
void conv3_head_kernel(const float* __restrict__ in, const float* __restrict__ wT,
                       const float* __restrict__ b_hm, const float* __restrict__ anchor_vecs,
                       const float* __restrict__ thr_scale, const float* __restrict__ logit_scale,
                       const float* __restrict__ logit_bias, float* __restrict__ heatmap) {
  const int CIN = 128, cobTot = 64;
  __shared__ float lds_in[8][6][68];
  const int x0 = blockIdx.x * 64;
  const int y0 = blockIdx.y * 4;
  const int b  = blockIdx.z;
  const int tid  = threadIdx.x;
  const int co_g = tid & 15;
  const int pg   = tid >> 4;
  const int pxb  = pg * 4;

  float acc[4][4][4];
#pragma unroll
  for (int a = 0; a < 4; ++a)
#pragma unroll
    for (int yy = 0; yy < 4; ++yy)
#pragma unroll
      for (int xx = 0; xx < 4; ++xx) acc[a][yy][xx] = 0.f;

  for (int c0 = 0; c0 < CIN; c0 += 8) {
    __syncthreads();
    for (int i = tid; i < 8 * 6 * 68; i += 256) {
      int ch = i / (6 * 68); int rem = i - ch * (6 * 68);
      int r = rem / 68; int xx = rem - r * 68;
      int y = y0 + r - 1; int x = x0 + xx - 1;
      float v = 0.f;
      if (xx < 66 && (unsigned)y < (unsigned)HW && (unsigned)x < (unsigned)HW)
        v = in[(((size_t)b * CIN + (c0 + ch)) * HW + y) * HW + x];
      lds_in[ch][r][xx] = v;
    }
    __syncthreads();
    for (int ch = 0; ch < 8; ++ch) {
      float rin[6][6];
#pragma unroll
      for (int rr = 0; rr < 6; ++rr) {
        const float2* rp = (const float2*)&lds_in[ch][rr][pxb];
        float2 v0 = rp[0], v1 = rp[1], v2 = rp[2];
        rin[rr][0] = v0.x; rin[rr][1] = v0.y; rin[rr][2] = v1.x;
        rin[rr][3] = v1.y; rin[rr][4] = v2.x; rin[rr][5] = v2.y;
      }
      const float* wrow = wT + (size_t)(c0 + ch) * 9 * cobTot + co_g * 4;
#pragma unroll
      for (int t = 0; t < 9; ++t) {
        const float4 w4 = *reinterpret_cast<const float4*>(wrow + (size_t)t * cobTot);
        const int ky = t / 3, kx = t % 3;
#pragma unroll
        for (int yy = 0; yy < 4; ++yy)
#pragma unroll
          for (int xx = 0; xx < 4; ++xx) {
            const float iv = rin[yy + ky][xx + kx];
            acc[0][yy][xx] = fmaf(iv, w4.x, acc[0][yy][xx]);
            acc[1][yy][xx] = fmaf(iv, w4.y, acc[1][yy][xx]);
            acc[2][yy][xx] = fmaf(iv, w4.z, acc[2][yy][xx]);
            acc[3][yy][xx] = fmaf(iv, w4.w, acc[3][yy][xx]);
          }
      }
    }
  }

  // ---- fused head epilogue ----
  const int c = co_g * 4;  // base of this thread's 4 channels
  float4 a4[10];
#pragma unroll
  for (int k = 0; k < 10; ++k) {
    if (c + 3 < TDIM) a4[k] = *reinterpret_cast<const float4*>(anchor_vecs + k * TDIM + c);
    else a4[k] = make_float4(0.f, 0.f, 0.f, 0.f);
  }
  float bh[4], th[4];
#pragma unroll
  for (int co = 0; co < 4; ++co) {
    int cc = c + co;
    bh[co] = (cc < TDIM) ? b_hm[cc] : 0.f;
    th[co] = (float)(TH_LO + (double)(cc % 20) * TH_STEP);
  }
  const float s  = thr_scale[0];
  const float ls = logit_scale[0];
  const float lb = logit_bias[0];
  const int xbase = x0 + pxb;

#pragma unroll
  for (int yy = 0; yy < 4; ++yy) {
#pragma unroll
    for (int xx = 0; xx < 4; ++xx) {
      float v[4];
#pragma unroll
      for (int co = 0; co < 4; ++co) {
        if (c + co < TDIM) {
          float z = acc[co][yy][xx] + bh[co];
          float t = (z - th[co]) * s;
          v[co] = 1.f / (1.f + expf(-t));
        } else v[co] = 0.f;
      }
      float s2 = v[0]*v[0] + v[1]*v[1] + v[2]*v[2] + v[3]*v[3];
      float dp[10];
#pragma unroll
      for (int k = 0; k < 10; ++k)
        dp[k] = v[0]*a4[k].x + v[1]*a4[k].y + v[2]*a4[k].z + v[3]*a4[k].w;
#pragma unroll
      for (int off = 1; off < 16; off <<= 1) {
        s2 += __shfl_xor(s2, off, 16);
#pragma unroll
        for (int k = 0; k < 10; ++k) dp[k] += __shfl_xor(dp[k], off, 16);
      }
      if (co_g < NCLS && xbase + xx < HW) {
        float dk = dp[0];
#pragma unroll
        for (int k = 1; k < 10; ++k) if (co_g == k) dk = dp[k];
        float sim = dk / (1e-8f + sqrtf(s2));
        float hm = 1.f / (1.f + expf(-fmaf(ls, sim, lb)));
        heatmap[(((size_t)b * NCLS + co_g) * HW + (y0 + yy)) * HW + (xbase + xx)] = hm;
      }
    }
  }
}

__global__ void sims_kernel(float* __restrict__ out_sims) {
  int t = threadIdx.x;
  if (t < 100) {
    int i = t / 10, j = t % 10;
    float r = 1.f;
#pragma unroll
    for (int d = 0; d < 3; ++d) {
      float ai = c_anchors[i][d], aj = c_anchors[j][d];
      r *= fminf(ai, aj) / fmaxf(ai, aj);
    }
    out_sims[t] = r;
  }
}

__global__ void nms_kernel(const float* __restrict__ hm, float* __restrict__ nms) {
  int i = blockIdx.x * 256 + threadIdx.x;
  if (i >= 2 * NBIG) return;
  int x = i % HW; int y = (i / HW) % HW; int bk = i / NPIX;
  float v = hm[i];
  float m = v;
#pragma unroll
  for (int dy = -1; dy <= 1; ++dy)
#pragma unroll
    for (int dx = -1; dx <= 1; ++dx) {
      int yy = y + dy, xx = x + dx;
      if ((unsigned)yy < (unsigned)HW && (unsigned)xx < (unsigned)HW)
        m = fmaxf(m, hm[((size_t)bk * NPIX) + yy * HW + xx]);
    }
  nms[i] = (v == m) ? v : 0.f;
}

// Per-batch exact top-200 (radix select on float bits, then bitonic sorts that
// reproduce jax.lax.top_k ordering: value desc, index asc on ties).
__global__ __launch_bounds__(1024)
void topk_kernel(const float* __restrict__ nms, const float* __restrict__ heatmap,
                 const float* __restrict__ bev_pos, float* __restrict__ out,
                 int* __restrict__ iws) {
  const int b = blockIdx.x;
  const int tid = threadIdx.x;
  const float* data = nms + (size_t)b * NBIG;

  __shared__ unsigned hist[256];
  __shared__ unsigned sh_prefix;
  __shared__ int sh_want;
  __shared__ int cntGT, cntTie;
  __shared__ unsigned gt_key[256], gt_idx[256];
  __shared__ unsigned tie_idx[2048];

  unsigned prefix = 0; int want = NPROP;
  for (int shift = 24; shift >= 0; shift -= 8) {
    if (tid < 256) hist[tid] = 0u;
    __syncthreads();
    for (int i = tid; i < NBIG; i += 1024) {
      unsigned k = __float_as_uint(data[i]);  // values >= 0 -> monotonic bits
      bool match = (shift == 24) || ((k >> (shift + 8)) == (prefix >> (shift + 8)));
      if (match) atomicAdd(&hist[(k >> shift) & 255], 1u);
    }
    __syncthreads();
    if (tid == 0) {
      int cum = 0; int bsel = 0; sh_want = want;
      for (int bin = 255; bin >= 0; --bin) {
        cum += (int)hist[bin];
        if (cum >= want) { bsel = bin; sh_want = want - (cum - (int)hist[bin]); break; }
      }
      sh_prefix = prefix | ((unsigned)bsel << shift);
      cntGT = 0; cntTie = 0;
    }
    __syncthreads();
    prefix = sh_prefix; want = sh_want;
    __syncthreads();
  }
  const unsigned T = prefix;  // key of the 200th largest

  for (int i = tid; i < NBIG; i += 1024) {
    unsigned k = __float_as_uint(data[i]);
    if (k > T) {
      int p = atomicAdd(&cntGT, 1);
      if (p < 256) { gt_key[p] = k; gt_idx[p] = (unsigned)i; }
    } else if (k == T) {
      int p = atomicAdd(&cntTie, 1);
      if (p < 2048) tie_idx[p] = (unsigned)i;
    }
  }
  __syncthreads();
  const int nGT = min(cntGT, 256);    // by construction <= 199
  const int nTie = min(cntTie, 2048);

  for (int i = tid; i < 256; i += 1024)
    if (i >= nGT) { gt_key[i] = 0u; gt_idx[i] = 0xFFFFFFFFu; }
  for (int i = tid; i < 2048; i += 1024)
    if (i >= nTie) tie_idx[i] = 0xFFFFFFFFu;
  __syncthreads();

  // bitonic sort GT: key desc, idx asc
  for (int k2 = 2; k2 <= 256; k2 <<= 1) {
    for (int j = k2 >> 1; j > 0; j >>= 1) {
      for (int i = tid; i < 256; i += 1024) {
        int ixj = i ^ j;
        if (ixj > i) {
          unsigned ka = gt_key[i], kb = gt_key[ixj];
          unsigned ia = gt_idx[i], ib = gt_idx[ixj];
          bool firstA = (ka > kb) || (ka == kb && ia < ib);
          bool up = ((i & k2) == 0);
          if (up ? !firstA : firstA) {
            gt_key[i] = kb; gt_key[ixj] = ka;
            gt_idx[i] = ib; gt_idx[ixj] = ia;
          }
        }
      }
      __syncthreads();
    }
  }
  // bitonic sort ties: idx asc
  for (int k2 = 2; k2 <= 2048; k2 <<= 1) {
    for (int j = k2 >> 1; j > 0; j >>= 1) {
      for (int i = tid; i < 2048; i += 1024) {
        int ixj = i ^ j;
        if (ixj > i) {
          unsigned ia = tie_idx[i], ib = tie_idx[ixj];
          bool firstA = ia < ib;
          bool up = ((i & k2) == 0);
          if (up ? !firstA : firstA) { tie_idx[i] = ib; tie_idx[ixj] = ia; }
        }
      }
      __syncthreads();
    }
  }

  for (int r = tid; r < NPROP; r += 1024) {
    unsigned idx; float score;
    if (r < nGT) { idx = gt_idx[r]; score = __uint_as_float(gt_key[r]); }
    else         { idx = tie_idx[r - nGT]; score = __uint_as_float(T); }
    int label = (int)(idx / NPIX);
    int pos = (int)(idx - (unsigned)label * NPIX);
    out[648000 + b * NPROP + r] = score;
    out[648400 + b * NPROP + r] = (float)label;
    out[700000 + (b * NPROP + r) * 2 + 0] = bev_pos[pos * 2 + 0];
    out[700000 + (b * NPROP + r) * 2 + 1] = bev_pos[pos * 2 + 1];
#pragma unroll
    for (int k = 0; k < NCLS; ++k)
      out[700800 + (b * NCLS + k) * NPROP + r] = heatmap[(size_t)(b * NCLS + k) * NPIX + pos];
    iws[b * NPROP + r] = pos;
    iws[2 * NPROP + b * NPROP + r] = label;
  }
}

__global__ void gather_qf_kernel(const float* __restrict__ lidar, const float* __restrict__ w_enc,
                                 const int* __restrict__ iws, float* __restrict__ out_qf) {
  int p = blockIdx.x % NPROP;
  int b = blockIdx.x / NPROP;
  int c = threadIdx.x;
  int pos = iws[b * NPROP + p];
  int label = iws[2 * NPROP + b * NPROP + p];
  float la0 = logf(c_anchors[label][0]);
  float la1 = logf(c_anchors[label][1]);
  float la2 = logf(c_anchors[label][2]);
  float dot = w_enc[c * 3 + 0] * la0 + w_enc[c * 3 + 1] * la1 + w_enc[c * 3 + 2] * la2;
  float g = lidar[((size_t)b * HID + c) * NPIX + pos];
  out_qf[((size_t)b * HID + c) * NPROP + p] = g + dot;
}

extern "C" void kernel_launch(void* const* d_in, const int* in_sizes, int n_in,
                              void* d_out, int out_size, void* d_ws, size_t ws_size,
                              hipStream_t stream) {
  (void)in_sizes; (void)n_in; (void)out_size; (void)ws_size;
  const float* feats       = (const float*)d_in[0];
  const float* w_shared    = (const float*)d_in[1];
  const float* b_shared    = (const float*)d_in[2];
  const float* w_bb        = (const float*)d_in[3];
  const float* gamma_bb    = (const float*)d_in[4];
  const float* beta_bb     = (const float*)d_in[5];
  const float* w_hm        = (const float*)d_in[6];
  const float* b_hm        = (const float*)d_in[7];
  const float* thr_scale   = (const float*)d_in[8];
  const float* logit_scale = (const float*)d_in[9];
  const float* logit_bias  = (const float*)d_in[10];
  const float* w_enc       = (const float*)d_in[11];
  const float* anchor_vecs = (const float*)d_in[12];
  const float* bev_pos     = (const float*)d_in[13];
  float* out = (float*)d_out;

  float* ws = (float*)d_ws;
  size_t off = 0;
  float* lidar = ws + off; off += (size_t)2 * HID * NPIX;   // 8,294,400
  float* xbb   = ws + off; off += (size_t)2 * HID * NPIX;   // 8,294,400
  float* nmsb  = ws + off; off += (size_t)2 * NBIG;         //   648,000
  float* wT1   = ws + off; off += (size_t)512 * 9 * 128;    //   589,824
  float* wT2   = ws + off; off += (size_t)128 * 9 * 128;    //   147,456
  float* wT3   = ws + off; off += (size_t)128 * 9 * 64;     //    73,728
  int*   iws   = (int*)(ws + off);                          //       800 ints

  transpose_w_kernel<<<(512*9*128 + 255)/256, 256, 0, stream>>>(w_shared, wT1, 512, 128, 128);
  transpose_w_kernel<<<(128*9*128 + 255)/256, 256, 0, stream>>>(w_bb,     wT2, 128, 128, 128);
  transpose_w_kernel<<<(128*9*64  + 255)/256, 256, 0, stream>>>(w_hm,     wT3, 128,  60,  64);

  dim3 cgrid(3, 45, 4);   // x-tiles, y-tiles, b*cout-halves
  conv3x3_kernel<512,0><<<cgrid, 256, 0, stream>>>(feats, wT1, b_shared, nullptr, lidar, 128);
  conv3x3_kernel<128,1><<<cgrid, 256, 0, stream>>>(lidar, wT2, gamma_bb, beta_bb, xbb, 128);

  dim3 hgrid(3, 45, 2);
  conv3_head_kernel<<<hgrid, 256, 0, stream>>>(xbb, wT3, b_hm, anchor_vecs,
                                               thr_scale, logit_scale, logit_bias, out);

  sims_kernel<<<1, 128, 0, stream>>>(out + 704800);
  nms_kernel<<<(2*NBIG + 255)/256, 256, 0, stream>>>(out, nmsb);
  topk_kernel<<<2, 1024, 0, stream>>>(nmsb, out, bev_pos, out, iws);
  gather_qf_kernel<<<2*NPROP, 128, 0, stream>>>(lidar, w_enc, iws, out + 648800);
}